// Round 1
// baseline (374.299 us; speedup 1.0000x reference)
//
#include <hip/hip_runtime.h>

#define B_ 4
#define T_ 1024
#define D_ 256
#define O_ 256
#define NC 32   // chunks along T
#define CL 32   // chunk length (NC*CL == T_)

// ---------------- Kernel A: per-chunk sums S[b,c,d] ----------------
__global__ __launch_bounds__(256) void chunk_sums(const float* __restrict__ x,
                                                  float* __restrict__ S) {
    const int d  = threadIdx.x;          // 0..255
    const int bc = blockIdx.x;           // b*NC + c
    const int b  = bc / NC;
    const int c  = bc % NC;
    const float* xp = x + ((size_t)b * T_ + (size_t)c * CL) * D_ + d;
    float s = 0.f;
#pragma unroll
    for (int i = 0; i < CL; ++i) s += xp[(size_t)i * D_];
    S[((size_t)b * NC + c) * D_ + d] = s;
}

// ---------------- Kernel B: cm[b,t,d] = cumsum(x)/ (t+1) ----------------
__global__ __launch_bounds__(256) void cumsum_mean(const float* __restrict__ x,
                                                   const float* __restrict__ S,
                                                   float* __restrict__ cm) {
    const int d  = threadIdx.x;
    const int bc = blockIdx.x;
    const int b  = bc / NC;
    const int c  = bc % NC;
    float off = 0.f;
    for (int cc = 0; cc < c; ++cc) off += S[((size_t)b * NC + cc) * D_ + d];
    const float* xp = x  + ((size_t)b * T_ + (size_t)c * CL) * D_ + d;
    float*       cp = cm + ((size_t)b * T_ + (size_t)c * CL) * D_ + d;
    float run = off;
#pragma unroll 4
    for (int i = 0; i < CL; ++i) {
        run += xp[(size_t)i * D_];
        const int t = c * CL + i;
        cp[(size_t)i * D_] = run / (float)(t + 1);   // IEEE divide, matches ref
    }
}

// ---------------- Kernel C: out[b,t,:] = cm[b,t,:] @ W[t] ----------------
// One block per t. tid&63 -> o-quad (float4 of W, coalesced 16B/lane).
// tid>>6 -> d-chunk of 64. 16 accumulators/thread (4 batch x 4 o).
__global__ __launch_bounds__(256) void gemm_t(const float* __restrict__ cm,
                                              const float* __restrict__ W,
                                              float* __restrict__ out) {
    const int t   = blockIdx.x;     // 0..1023
    const int tid = threadIdx.x;    // 0..255
    const int oq  = tid & 63;       // o-quad index, o = oq*4
    const int dc  = tid >> 6;       // d-chunk 0..3

    __shared__ float cml[D_][4];        // [d][b], 4 KB; b128 broadcast reads
    __shared__ float red[4][64][17];    // +1 pad -> conflict-free reduce, ~17.4 KB

    // Stage cm[:, t, :] into LDS as [d][b] (coalesced over d per b)
#pragma unroll
    for (int b = 0; b < 4; ++b)
        cml[tid][b] = cm[((size_t)b * T_ + t) * D_ + tid];
    __syncthreads();

    const float* Wp = W + ((size_t)t * D_ + (size_t)dc * 64) * O_ + (size_t)oq * 4;

    float4 a0 = make_float4(0.f, 0.f, 0.f, 0.f);
    float4 a1 = a0, a2 = a0, a3 = a0;

#pragma unroll 8
    for (int i = 0; i < 64; ++i) {
        const float4 w  = *(const float4*)(Wp + (size_t)i * O_);
        const float4 c4 = *(const float4*)cml[dc * 64 + i];   // broadcast, no conflict
        a0.x += c4.x * w.x; a0.y += c4.x * w.y; a0.z += c4.x * w.z; a0.w += c4.x * w.w;
        a1.x += c4.y * w.x; a1.y += c4.y * w.y; a1.z += c4.y * w.z; a1.w += c4.y * w.w;
        a2.x += c4.z * w.x; a2.y += c4.z * w.y; a2.z += c4.z * w.z; a2.w += c4.z * w.w;
        a3.x += c4.w * w.x; a3.y += c4.w * w.y; a3.z += c4.w * w.z; a3.w += c4.w * w.w;
    }

    // Cross-d-chunk reduction through padded LDS
    float* r = red[dc][oq];
    r[ 0] = a0.x; r[ 1] = a0.y; r[ 2] = a0.z; r[ 3] = a0.w;
    r[ 4] = a1.x; r[ 5] = a1.y; r[ 6] = a1.z; r[ 7] = a1.w;
    r[ 8] = a2.x; r[ 9] = a2.y; r[10] = a2.z; r[11] = a2.w;
    r[12] = a3.x; r[13] = a3.y; r[14] = a3.z; r[15] = a3.w;
    __syncthreads();

    if (tid < 64) {
        float v[16];
#pragma unroll
        for (int k = 0; k < 16; ++k)
            v[k] = red[0][tid][k] + red[1][tid][k] + red[2][tid][k] + red[3][tid][k];
#pragma unroll
        for (int b = 0; b < 4; ++b) {
            float4 o4 = make_float4(v[b * 4 + 0], v[b * 4 + 1], v[b * 4 + 2], v[b * 4 + 3]);
            *(float4*)&out[((size_t)b * T_ + t) * O_ + (size_t)tid * 4] = o4;
        }
    }
}

extern "C" void kernel_launch(void* const* d_in, const int* in_sizes, int n_in,
                              void* d_out, int out_size, void* d_ws, size_t ws_size,
                              hipStream_t stream) {
    const float* x = (const float*)d_in[0];   // (B,T,D) f32
    const float* W = (const float*)d_in[1];   // (T,D,O) f32
    float* out = (float*)d_out;               // (B,T,O) f32

    float* cm = (float*)d_ws;                        // B*T*D floats = 4 MB
    float* S  = (float*)d_ws + (size_t)B_ * T_ * D_; // B*NC*D floats = 128 KB

    chunk_sums <<<B_ * NC, 256, 0, stream>>>(x, S);
    cumsum_mean<<<B_ * NC, 256, 0, stream>>>(x, S, cm);
    gemm_t     <<<T_,      256, 0, stream>>>(cm, W, out);
}

// Round 3
// 353.093 us; speedup vs baseline: 1.0601x; 1.0601x over previous
//
#include <hip/hip_runtime.h>

#define B_ 4
#define T_ 1024
#define D_ 256
#define O_ 256
#define NC 32   // chunks along T
#define CL 32   // chunk length (NC*CL == T_)

typedef float v4f __attribute__((ext_vector_type(4)));  // nontemporal-compatible

// ---------------- Kernel A: per-chunk sums S[b,c,d] ----------------
__global__ __launch_bounds__(256) void chunk_sums(const float* __restrict__ x,
                                                  float* __restrict__ S) {
    const int d  = threadIdx.x;          // 0..255
    const int bc = blockIdx.x;           // b*NC + c
    const int b  = bc / NC;
    const int c  = bc % NC;
    const float* xp = x + ((size_t)b * T_ + (size_t)c * CL) * D_ + d;
    float s = 0.f;
#pragma unroll
    for (int i = 0; i < CL; ++i) s += xp[(size_t)i * D_];
    S[((size_t)b * NC + c) * D_ + d] = s;
}

// ---------------- Kernel B: cm[b,t,d] = cumsum(x)/(t+1) ----------------
__global__ __launch_bounds__(256) void cumsum_mean(const float* __restrict__ x,
                                                   const float* __restrict__ S,
                                                   float* __restrict__ cm) {
    const int d  = threadIdx.x;
    const int bc = blockIdx.x;
    const int b  = bc / NC;
    const int c  = bc % NC;
    float off = 0.f;
    for (int cc = 0; cc < c; ++cc) off += S[((size_t)b * NC + cc) * D_ + d];
    const float* xp = x  + ((size_t)b * T_ + (size_t)c * CL) * D_ + d;
    float*       cp = cm + ((size_t)b * T_ + (size_t)c * CL) * D_ + d;
    float run = off;
#pragma unroll 4
    for (int i = 0; i < CL; ++i) {
        run += xp[(size_t)i * D_];
        const int t = c * CL + i;
        cp[(size_t)i * D_] = run / (float)(t + 1);   // IEEE divide, matches ref
    }
}

// ---------------- Kernel C: out[b,t,:] = cm[b,t,:] @ W[t] ----------------
// One block per t. tid&63 -> o-quad (v4f of W, 1KB/wave coalesced).
// tid>>6 -> d-chunk of 64. W read exactly once, nontemporal (stream-once).
__global__ __launch_bounds__(256, 4) void gemm_t(const float* __restrict__ cm,
                                                 const float* __restrict__ W,
                                                 float* __restrict__ out) {
    const int t   = blockIdx.x;     // 0..1023
    const int tid = threadIdx.x;    // 0..255
    const int oq  = tid & 63;       // o-quad index, o = oq*4
    const int dc  = tid >> 6;       // d-chunk 0..3

    __shared__ float cml[D_][4];        // [d][b], broadcast b128 reads
    __shared__ float red[4][64][17];    // stride 17 -> all 32 banks, 2-way (free)

    // Stage cm[:, t, :] into LDS as [d][b]
#pragma unroll
    for (int b = 0; b < 4; ++b)
        cml[tid][b] = cm[((size_t)b * T_ + t) * D_ + tid];
    __syncthreads();

    const v4f* Wp = (const v4f*)(W + ((size_t)t * D_ + (size_t)dc * 64) * O_) + oq;

    v4f a0 = (v4f)(0.f), a1 = (v4f)(0.f), a2 = (v4f)(0.f), a3 = (v4f)(0.f);

#pragma unroll 8
    for (int i = 0; i < 64; ++i) {
        const v4f w  = __builtin_nontemporal_load(Wp + (size_t)i * (O_ / 4));
        const v4f c4 = *(const v4f*)cml[dc * 64 + i];   // wave-uniform broadcast
        a0 += c4.x * w;
        a1 += c4.y * w;
        a2 += c4.z * w;
        a3 += c4.w * w;
    }

    // Stash partials: red[dc][oq][b*4+k]
    float* r = red[dc][oq];
    r[ 0] = a0.x; r[ 1] = a0.y; r[ 2] = a0.z; r[ 3] = a0.w;
    r[ 4] = a1.x; r[ 5] = a1.y; r[ 6] = a1.z; r[ 7] = a1.w;
    r[ 8] = a2.x; r[ 9] = a2.y; r[10] = a2.z; r[11] = a2.w;
    r[12] = a3.x; r[13] = a3.y; r[14] = a3.z; r[15] = a3.w;
    __syncthreads();

    // Parallel epilogue: thread (b2=tid>>6, oq2=tid&63) writes one v4f.
    {
        const int b2  = tid >> 6;
        const int oq2 = tid & 63;
        v4f v;
        v.x = red[0][oq2][b2 * 4 + 0] + red[1][oq2][b2 * 4 + 0]
            + red[2][oq2][b2 * 4 + 0] + red[3][oq2][b2 * 4 + 0];
        v.y = red[0][oq2][b2 * 4 + 1] + red[1][oq2][b2 * 4 + 1]
            + red[2][oq2][b2 * 4 + 1] + red[3][oq2][b2 * 4 + 1];
        v.z = red[0][oq2][b2 * 4 + 2] + red[1][oq2][b2 * 4 + 2]
            + red[2][oq2][b2 * 4 + 2] + red[3][oq2][b2 * 4 + 2];
        v.w = red[0][oq2][b2 * 4 + 3] + red[1][oq2][b2 * 4 + 3]
            + red[2][oq2][b2 * 4 + 3] + red[3][oq2][b2 * 4 + 3];
        __builtin_nontemporal_store(v,
            (v4f*)&out[((size_t)b2 * T_ + t) * O_ + (size_t)oq2 * 4]);
    }
}

extern "C" void kernel_launch(void* const* d_in, const int* in_sizes, int n_in,
                              void* d_out, int out_size, void* d_ws, size_t ws_size,
                              hipStream_t stream) {
    const float* x = (const float*)d_in[0];   // (B,T,D) f32
    const float* W = (const float*)d_in[1];   // (T,D,O) f32
    float* out = (float*)d_out;               // (B,T,O) f32

    float* cm = (float*)d_ws;                        // B*T*D floats = 4 MB
    float* S  = (float*)d_ws + (size_t)B_ * T_ * D_; // B*NC*D floats = 128 KB

    chunk_sums <<<B_ * NC, 256, 0, stream>>>(x, S);
    cumsum_mean<<<B_ * NC, 256, 0, stream>>>(x, S, cm);
    gemm_t     <<<T_,      256, 0, stream>>>(cm, W, out);
}

// Round 4
// 343.888 us; speedup vs baseline: 1.0884x; 1.0268x over previous
//
#include <hip/hip_runtime.h>

#define B_ 4
#define T_ 1024
#define D_ 256
#define O_ 256
#define NC 32   // chunks along T
#define CL 32   // chunk length (NC*CL == T_)

typedef float v4f __attribute__((ext_vector_type(4)));  // nontemporal-compatible

// ---------------- Kernel A: per-chunk sums S[b,c,d] ----------------
__global__ __launch_bounds__(256) void chunk_sums(const float* __restrict__ x,
                                                  float* __restrict__ S) {
    const int d  = threadIdx.x;          // 0..255
    const int bc = blockIdx.x;           // b*NC + c
    const int b  = bc / NC;
    const int c  = bc % NC;
    const float* xp = x + ((size_t)b * T_ + (size_t)c * CL) * D_ + d;
    float s = 0.f;
#pragma unroll
    for (int i = 0; i < CL; ++i) s += xp[(size_t)i * D_];
    S[((size_t)b * NC + c) * D_ + d] = s;
}

// ---------------- Kernel B: cm[b,t,d] = cumsum(x)/(t+1) ----------------
__global__ __launch_bounds__(256) void cumsum_mean(const float* __restrict__ x,
                                                   const float* __restrict__ S,
                                                   float* __restrict__ cm) {
    const int d  = threadIdx.x;
    const int bc = blockIdx.x;
    const int b  = bc / NC;
    const int c  = bc % NC;
    // Masked full-unroll: all 32 loads independent & in flight, one latency.
    float off = 0.f;
#pragma unroll
    for (int cc = 0; cc < NC; ++cc) {
        const float v = S[((size_t)b * NC + cc) * D_ + d];
        off += (cc < c) ? v : 0.f;
    }
    const float* xp = x  + ((size_t)b * T_ + (size_t)c * CL) * D_ + d;
    float*       cp = cm + ((size_t)b * T_ + (size_t)c * CL) * D_ + d;
    float run = off;
#pragma unroll 4
    for (int i = 0; i < CL; ++i) {
        run += xp[(size_t)i * D_];
        const int t = c * CL + i;
        cp[(size_t)i * D_] = run / (float)(t + 1);   // IEEE divide, matches ref
    }
}

// ---------------- Kernel C: out[b,t,:] = cm[b,t,:] @ W[t] ----------------
// Grid 256 blocks (1/CU), block handles 4 consecutive t. Wave tq streams
// W[t0+tq] as one linear 256 KB nontemporal stream. Thread (tq, oq) owns all
// 256 d for its o-quad: no reduction LDS, no epilogue barrier, direct stores.
__global__ __launch_bounds__(256) void gemm_t(const float* __restrict__ cm,
                                              const float* __restrict__ W,
                                              float* __restrict__ out) {
    const int t0  = blockIdx.x * 4;
    const int tid = threadIdx.x;
    const int tq  = tid >> 6;       // which t within the block (== wave id)
    const int oq  = tid & 63;       // o-quad, o = oq*4

    __shared__ float cml[4][D_][4];   // [tq][d][b], 16 KB; broadcast b128 reads

    // Stage cm rows t0..t0+3 (coalesced over d)
#pragma unroll
    for (int q = 0; q < 4; ++q)
#pragma unroll
        for (int b = 0; b < 4; ++b)
            cml[q][tid][b] = cm[((size_t)b * T_ + t0 + q) * D_ + tid];
    __syncthreads();

    const v4f* Wp = (const v4f*)(W + (size_t)(t0 + tq) * D_ * O_) + oq;

    v4f a0 = (v4f)(0.f), a1 = (v4f)(0.f), a2 = (v4f)(0.f), a3 = (v4f)(0.f);

    v4f w[16];
    // preload first half (d = 0..7)
#pragma unroll
    for (int j = 0; j < 8; ++j)
        w[j] = __builtin_nontemporal_load(Wp + (size_t)j * (O_ / 4));

#pragma unroll 1
    for (int dd = 0; dd < D_; dd += 16) {
        // load second half (d = dd+8 .. dd+15)
#pragma unroll
        for (int j = 0; j < 8; ++j)
            w[8 + j] = __builtin_nontemporal_load(Wp + (size_t)(dd + 8 + j) * (O_ / 4));
        // compute first half
#pragma unroll
        for (int j = 0; j < 8; ++j) {
            const v4f c4 = *(const v4f*)cml[tq][dd + j];
            a0 += c4.x * w[j]; a1 += c4.y * w[j]; a2 += c4.z * w[j]; a3 += c4.w * w[j];
        }
        // load next first half (d = dd+16 .. dd+23)
        if (dd + 16 < D_) {
#pragma unroll
            for (int j = 0; j < 8; ++j)
                w[j] = __builtin_nontemporal_load(Wp + (size_t)(dd + 16 + j) * (O_ / 4));
        }
        // compute second half
#pragma unroll
        for (int j = 0; j < 8; ++j) {
            const v4f c4 = *(const v4f*)cml[tq][dd + 8 + j];
            a0 += c4.x * w[8 + j]; a1 += c4.y * w[8 + j];
            a2 += c4.z * w[8 + j]; a3 += c4.w * w[8 + j];
        }
    }

    // Direct per-thread stores: out[b, t0+tq, oq*4..+3]
    const size_t obase = (size_t)(t0 + tq) * O_ + (size_t)oq * 4;
    __builtin_nontemporal_store(a0, (v4f*)&out[(size_t)0 * T_ * O_ + obase]);
    __builtin_nontemporal_store(a1, (v4f*)&out[(size_t)1 * T_ * O_ + obase]);
    __builtin_nontemporal_store(a2, (v4f*)&out[(size_t)2 * T_ * O_ + obase]);
    __builtin_nontemporal_store(a3, (v4f*)&out[(size_t)3 * T_ * O_ + obase]);
}

extern "C" void kernel_launch(void* const* d_in, const int* in_sizes, int n_in,
                              void* d_out, int out_size, void* d_ws, size_t ws_size,
                              hipStream_t stream) {
    const float* x = (const float*)d_in[0];   // (B,T,D) f32
    const float* W = (const float*)d_in[1];   // (T,D,O) f32
    float* out = (float*)d_out;               // (B,T,O) f32

    float* cm = (float*)d_ws;                        // B*T*D floats = 4 MB
    float* S  = (float*)d_ws + (size_t)B_ * T_ * D_; // B*NC*D floats = 128 KB

    chunk_sums <<<B_ * NC, 256, 0, stream>>>(x, S);
    cumsum_mean<<<B_ * NC, 256, 0, stream>>>(x, S, cm);
    gemm_t     <<<T_ / 4,  256, 0, stream>>>(cm, W, out);
}